// Round 1
// baseline (191.502 us; speedup 1.0000x reference)
//
#include <hip/hip_runtime.h>
#include <math.h>

#define HIDDEN 128
#define C4 (HIDDEN / 4)     // 32 float4 per row
#define RGROUPS 8           // 256 threads / 32 float4-columns
#define BLOCK 256

__device__ __forceinline__ int lower_bound(const int* __restrict__ a, int n, int val) {
    int lo = 0, hi = n;
    while (lo < hi) {
        int mid = (lo + hi) >> 1;
        if (a[mid] < val) lo = mid + 1; else hi = mid;
    }
    return lo;
}

__global__ __launch_bounds__(BLOCK) void MinMaxMeanPooling_kernel(
        const float* __restrict__ x, const int* __restrict__ batch,
        float* __restrict__ out, int N) {
    const int g = blockIdx.x;

    __shared__ int s_bounds[2];
    if (threadIdx.x == 0)   s_bounds[0] = lower_bound(batch, N, g);
    if (threadIdx.x == 128) s_bounds[1] = lower_bound(batch, N, g + 1);
    __syncthreads();
    const int start = s_bounds[0];
    const int end   = s_bounds[1];
    const int cnt   = end - start;

    const int t = threadIdx.x;
    const int c = t & (C4 - 1);   // float4 column 0..31
    const int r = t >> 5;         // row group 0..7

    float4 vmin = make_float4( INFINITY,  INFINITY,  INFINITY,  INFINITY);
    float4 vmax = make_float4(-INFINITY, -INFINITY, -INFINITY, -INFINITY);
    float4 vsum = make_float4(0.f, 0.f, 0.f, 0.f);

    const float4* __restrict__ x4 = (const float4*)x;
    for (int row = start + r; row < end; row += RGROUPS) {
        float4 v = x4[(long long)row * C4 + c];
        vmin.x = fminf(vmin.x, v.x); vmin.y = fminf(vmin.y, v.y);
        vmin.z = fminf(vmin.z, v.z); vmin.w = fminf(vmin.w, v.w);
        vmax.x = fmaxf(vmax.x, v.x); vmax.y = fmaxf(vmax.y, v.y);
        vmax.z = fmaxf(vmax.z, v.z); vmax.w = fmaxf(vmax.w, v.w);
        vsum.x += v.x; vsum.y += v.y; vsum.z += v.z; vsum.w += v.w;
    }

    __shared__ float4 smin[RGROUPS][C4];
    __shared__ float4 smax[RGROUPS][C4];
    __shared__ float4 ssum[RGROUPS][C4];
    smin[r][c] = vmin; smax[r][c] = vmax; ssum[r][c] = vsum;
    __syncthreads();

    #pragma unroll
    for (int s = RGROUPS / 2; s > 0; s >>= 1) {
        if (r < s) {
            float4 a, b;
            a = smin[r][c]; b = smin[r + s][c];
            a.x = fminf(a.x, b.x); a.y = fminf(a.y, b.y);
            a.z = fminf(a.z, b.z); a.w = fminf(a.w, b.w);
            smin[r][c] = a;
            a = smax[r][c]; b = smax[r + s][c];
            a.x = fmaxf(a.x, b.x); a.y = fmaxf(a.y, b.y);
            a.z = fmaxf(a.z, b.z); a.w = fmaxf(a.w, b.w);
            smax[r][c] = a;
            a = ssum[r][c]; b = ssum[r + s][c];
            a.x += b.x; a.y += b.y; a.z += b.z; a.w += b.w;
            ssum[r][c] = a;
        }
        __syncthreads();
    }

    if (t < C4) {
        float4 mn = smin[0][t];
        float4 mx = smax[0][t];
        float4 sm = ssum[0][t];
        float inv = 1.0f / (float)(cnt > 0 ? cnt : 1);
        float4 mean = make_float4(sm.x * inv, sm.y * inv, sm.z * inv, sm.w * inv);
        if (cnt == 0) {
            mn = make_float4(0.f, 0.f, 0.f, 0.f);
            mx = make_float4(0.f, 0.f, 0.f, 0.f);
            mean = make_float4(0.f, 0.f, 0.f, 0.f);
        }
        float* orow = out + (long long)g * (3 * HIDDEN);
        ((float4*)orow)[t] = mn;
        ((float4*)(orow + HIDDEN))[t] = mx;
        ((float4*)(orow + 2 * HIDDEN))[t] = mean;
    }
}

extern "C" void kernel_launch(void* const* d_in, const int* in_sizes, int n_in,
                              void* d_out, int out_size, void* d_ws, size_t ws_size,
                              hipStream_t stream) {
    const float* x     = (const float*)d_in[0];
    const int*   batch = (const int*)d_in[1];
    float*       out   = (float*)d_out;
    const int N = in_sizes[1];                  // number of nodes
    const int G = out_size / (3 * HIDDEN);      // number of segments (4096)
    MinMaxMeanPooling_kernel<<<G, BLOCK, 0, stream>>>(x, batch, out, N);
}

// Round 3
// 167.777 us; speedup vs baseline: 1.1414x; 1.1414x over previous
//
#include <hip/hip_runtime.h>
#include <math.h>

#define HIDDEN 128
#define C4 (HIDDEN / 4)     // 32 float4 per row
#define RGROUPS 8           // 256 threads / 32 float4-columns
#define BLOCK 256

typedef float f4 __attribute__((ext_vector_type(4)));   // native vector: OK for nontemporal builtins

__device__ __forceinline__ int lower_bound(const int* __restrict__ a, int n, int val) {
    int lo = 0, hi = n;
    while (lo < hi) {
        int mid = (lo + hi) >> 1;
        if (a[mid] < val) lo = mid + 1; else hi = mid;
    }
    return lo;
}

__device__ __forceinline__ f4 min4(f4 a, f4 b) {
    f4 r; r.x = fminf(a.x, b.x); r.y = fminf(a.y, b.y);
    r.z = fminf(a.z, b.z); r.w = fminf(a.w, b.w); return r;
}
__device__ __forceinline__ f4 max4(f4 a, f4 b) {
    f4 r; r.x = fmaxf(a.x, b.x); r.y = fmaxf(a.y, b.y);
    r.z = fmaxf(a.z, b.z); r.w = fmaxf(a.w, b.w); return r;
}

__global__ __launch_bounds__(BLOCK) void MinMaxMeanPooling_kernel(
        const float* __restrict__ x, const int* __restrict__ batch,
        float* __restrict__ out, int N) {
    const int g = blockIdx.x;

    __shared__ int s_bounds[2];
    if (threadIdx.x == 0)   s_bounds[0] = lower_bound(batch, N, g);
    if (threadIdx.x == 128) s_bounds[1] = lower_bound(batch, N, g + 1);
    __syncthreads();
    const int start = s_bounds[0];
    const int end   = s_bounds[1];
    const int cnt   = end - start;

    const int t = threadIdx.x;
    const int c = t & (C4 - 1);   // float4 column 0..31
    const int r = t >> 5;         // row group 0..7

    f4 vmin0 = (f4)( INFINITY);
    f4 vmax0 = (f4)(-INFINITY);
    f4 vsum0 = (f4)(0.f);
    f4 vmin1 = vmin0, vmax1 = vmax0, vsum1 = vsum0;

    const f4* __restrict__ p = (const f4*)x + (long long)(start + r) * C4 + c;
    int row = start + r;

    // unrolled x2: two independent loads in flight per iteration
    for (; row + RGROUPS < end; row += 2 * RGROUPS, p += 2 * RGROUPS * C4) {
        f4 v0 = __builtin_nontemporal_load(p);
        f4 v1 = __builtin_nontemporal_load(p + RGROUPS * C4);
        vmin0 = min4(vmin0, v0); vmax0 = max4(vmax0, v0); vsum0 += v0;
        vmin1 = min4(vmin1, v1); vmax1 = max4(vmax1, v1); vsum1 += v1;
    }
    if (row < end) {
        f4 v0 = __builtin_nontemporal_load(p);
        vmin0 = min4(vmin0, v0); vmax0 = max4(vmax0, v0); vsum0 += v0;
    }
    vmin0 = min4(vmin0, vmin1); vmax0 = max4(vmax0, vmax1); vsum0 += vsum1;

    __shared__ f4 smin[RGROUPS][C4];
    __shared__ f4 smax[RGROUPS][C4];
    __shared__ f4 ssum[RGROUPS][C4];
    smin[r][c] = vmin0; smax[r][c] = vmax0; ssum[r][c] = vsum0;
    __syncthreads();

    #pragma unroll
    for (int s = RGROUPS / 2; s > 0; s >>= 1) {
        if (r < s) {
            smin[r][c] = min4(smin[r][c], smin[r + s][c]);
            smax[r][c] = max4(smax[r][c], smax[r + s][c]);
            ssum[r][c] = ssum[r][c] + ssum[r + s][c];
        }
        __syncthreads();
    }

    if (t < C4) {
        f4 mn = smin[0][t];
        f4 mx = smax[0][t];
        f4 sm = ssum[0][t];
        float inv = 1.0f / (float)(cnt > 0 ? cnt : 1);
        f4 mean = sm * inv;
        if (cnt == 0) {
            mn = (f4)(0.f); mx = (f4)(0.f); mean = (f4)(0.f);
        }
        float* orow = out + (long long)g * (3 * HIDDEN);
        ((f4*)orow)[t] = mn;
        ((f4*)(orow + HIDDEN))[t] = mx;
        ((f4*)(orow + 2 * HIDDEN))[t] = mean;
    }
}

extern "C" void kernel_launch(void* const* d_in, const int* in_sizes, int n_in,
                              void* d_out, int out_size, void* d_ws, size_t ws_size,
                              hipStream_t stream) {
    const float* x     = (const float*)d_in[0];
    const int*   batch = (const int*)d_in[1];
    float*       out   = (float*)d_out;
    const int N = in_sizes[1];                  // number of nodes
    const int G = out_size / (3 * HIDDEN);      // number of segments (4096)
    MinMaxMeanPooling_kernel<<<G, BLOCK, 0, stream>>>(x, batch, out, N);
}